// Round 11
// baseline (766.586 us; speedup 1.0000x reference)
//
#include <hip/hip_runtime.h>
#include <cfloat>

#define BB 64
#define NPERB 2048
#define KNN 16
#define NTOT (BB*NPERB)
#define NCAND 24

typedef __bf16 bf16x8 __attribute__((ext_vector_type(8)));
typedef float  f32x4  __attribute__((ext_vector_type(4)));

__device__ __forceinline__ unsigned int med3u(unsigned int a, unsigned int b, unsigned int c) {
    unsigned int d;
    asm("v_med3_u32 %0, %1, %2, %3" : "=v"(d) : "v"(a), "v"(b), "v"(c));
    return d;
}

// numpy pairwise_sum (scalar 8-accumulator path) of x_f^2 over 64 contiguous fp32
__device__ __forceinline__ float np_sq64(const float* __restrict__ xs) {
    float r[8];
#pragma unroll
    for (int j = 0; j < 8; ++j) r[j] = __fmul_rn(xs[j], xs[j]);
#pragma unroll
    for (int i = 1; i < 8; ++i)
#pragma unroll
        for (int j = 0; j < 8; ++j)
            r[j] = __fadd_rn(r[j], __fmul_rn(xs[8*i + j], xs[8*i + j]));
    float t01 = __fadd_rn(r[0], r[1]);
    float t23 = __fadd_rn(r[2], r[3]);
    float t45 = __fadd_rn(r[4], r[5]);
    float t67 = __fadd_rn(r[6], r[7]);
    return __fadd_rn(__fadd_rn(t01, t23), __fadd_rn(t45, t67));
}

__device__ __forceinline__ unsigned short bf16rn(float f) {
    unsigned int u = __float_as_uint(f);
    u += 0x7fffu + ((u >> 16) & 1u);
    return (unsigned short)(u >> 16);
}
__device__ __forceinline__ unsigned int pk2(float a, float b) {
    return ((unsigned int)bf16rn(b) << 16) | (unsigned int)bf16rn(a);
}

// Kernel 1: A -> out (in place for k3), Bv, numpy-order sq, bf16 copy of x.
// Weights held transposed+padded in LDS so the inner loop is b128 LDS reads.
__global__ __launch_bounds__(256) void k_transform(const float* __restrict__ x,
    const float* __restrict__ w, const float* __restrict__ bias,
    float* __restrict__ Aout, float* __restrict__ Bvv, float* __restrict__ sqnp,
    unsigned int* __restrict__ xbu)
{
    __shared__ __align__(16) float w1mT[64*68];   // [o][f], stride 68 (16B-aligned rows)
    __shared__ __align__(16) float w2tT[64*68];
    __shared__ __align__(16) float xs[128*64];
    int t = threadIdx.x;
    int r0 = blockIdx.x * 128;
#pragma unroll
    for (int i = 0; i < 16; ++i) {
        int e = t + i*256; int o = e >> 6; int f = e & 63;
        float w1 = w[o*128 + f];
        float w2 = w[o*128 + 64 + f];
        w1mT[o*68 + f] = w1 - w2;
        w2tT[o*68 + f] = w2;
    }
#pragma unroll
    for (int i = 0; i < 32; ++i) { int idx = t + i*256; xs[idx] = x[(size_t)r0*64 + idx]; }
    __syncthreads();
    // bf16 copy: 128 rows x 32 uint pairs
#pragma unroll
    for (int i = 0; i < 16; ++i) {
        int e = t + i*256;
        xbu[(size_t)r0*32 + e] = pk2(xs[2*e], xs[2*e + 1]);
    }
    int o = t & 63;
    int rl0 = t >> 6;
    float br = bias[o];
    for (int g = 0; g < 32; ++g) {
        int rl = g*4 + rl0;
        float a1 = 0.f, a2 = 0.f;
#pragma unroll
        for (int f4 = 0; f4 < 16; ++f4) {
            float4 xv = *(const float4*)&xs[rl*64 + f4*4];
            float4 wa = *(const float4*)&w1mT[o*68 + f4*4];
            float4 wb = *(const float4*)&w2tT[o*68 + f4*4];
            a1 = fmaf(xv.x, wa.x, a1); a1 = fmaf(xv.y, wa.y, a1);
            a1 = fmaf(xv.z, wa.z, a1); a1 = fmaf(xv.w, wa.w, a1);
            a2 = fmaf(xv.x, wb.x, a2); a2 = fmaf(xv.y, wb.y, a2);
            a2 = fmaf(xv.z, wb.z, a2); a2 = fmaf(xv.w, wb.w, a2);
        }
        int row = r0 + rl;
        Aout[(size_t)row*64 + o] = a1 + br;
        Bvv[(size_t)row*64 + o] = a2;
        if (o == 0) sqnp[row] = np_sq64(&xs[rl*64]);
    }
}

// Kernel 2: barrier-free scan — MFMA fragments straight from global (L2-resident bf16 xb),
// med3 flat-16 in-register filter; then merge top-24 -> np-exact rescore -> exact top-16.
__global__ __launch_bounds__(256, 6) void k_topk(const float4* __restrict__ x4,
    const uint4* __restrict__ xbu, const float* __restrict__ sq, int* __restrict__ nbr)
{
    __shared__ __align__(16) unsigned int cand[64*68];      // 17408 B
    __shared__ unsigned short cand24[64*NCAND];             // 3072 B

    int t = threadIdx.x;
    int lane = t & 63;
    int w = t >> 6;
    int ln = lane & 15, qd = lane >> 4;
    int batch = blockIdx.x >> 5;
    int strip = blockIdx.x & 31;
    int rbase = batch * NPERB;
    int r0g = rbase + strip * 64;

    // row fragments direct from global bf16
    int myrow = r0g + w*16 + ln;
    bf16x8 rf0, rf1;
    { uint4 v0 = xbu[(size_t)myrow*8 + qd];     rf0 = *(bf16x8*)&v0; }
    { uint4 v1 = xbu[(size_t)myrow*8 + 4 + qd]; rf1 = *(bf16x8*)&v1; }
    float sqr16 = sq[myrow] + 16.f;

    unsigned int ks[16];
#pragma unroll
    for (int j = 0; j < 16; ++j) ks[j] = 0xFFFFFFFFu;

    for (int ct = 0; ct < 32; ++ct) {
        int cb = ct * 64;
#pragma unroll
        for (int ct2 = 0; ct2 < 4; ++ct2) {
            int pt = rbase + cb + ct2*16 + ln;
            uint4 va = xbu[(size_t)pt*8 + qd];
            uint4 vb = xbu[(size_t)pt*8 + 4 + qd];
            bf16x8 a0 = *(bf16x8*)&va;
            bf16x8 a1 = *(bf16x8*)&vb;
            f32x4 acc = {0.f, 0.f, 0.f, 0.f};
            acc = __builtin_amdgcn_mfma_f32_16x16x32_bf16(a0, rf0, acc, 0, 0, 0);
            acc = __builtin_amdgcn_mfma_f32_16x16x32_bf16(a1, rf1, acc, 0, 0, 0);
            float4 sq4 = *(const float4*)&sq[rbase + cb + ct2*16 + qd*4];
            int idxb = cb + ct2*16 + qd*4;
#pragma unroll
            for (int j = 0; j < 4; ++j) {
                float base = (j == 0 ? sq4.x : j == 1 ? sq4.y : j == 2 ? sq4.z : sq4.w) + sqr16;
                float s = fmaf(-2.f, acc[j], base);   // > 0 always
                unsigned int u = (__float_as_uint(s) & 0xFFFFF800u) | (unsigned int)(idxb + j);
#pragma unroll
                for (int jj = 15; jj >= 1; --jj) ks[jj] = med3u(u, ks[jj-1], ks[jj]);
                ks[0] = min(ks[0], u);
            }
        }
    }
    __syncthreads();   // waves desynced during scan; re-converge before the shared dump

    // dump per-lane keys: row = w*16+ln, quarter qd
    {
        int r = w*16 + ln;
#pragma unroll
        for (int j = 0; j < 16; ++j) cand[r*68 + qd*16 + j] = ks[j];
    }
    __syncthreads();

    // merge to bf16-top-24 per row
    if (t < 64) {
        unsigned int m24[NCAND];
#pragma unroll
        for (int j = 0; j < NCAND; ++j) m24[j] = 0xFFFFFFFFu;
        for (int i = 0; i < 64; ++i) {
            unsigned int u = cand[t*68 + i];
#pragma unroll
            for (int jj = NCAND-1; jj >= 1; --jj) m24[jj] = med3u(u, m24[jj-1], m24[jj]);
            m24[0] = min(m24[0], u);
        }
#pragma unroll
        for (int j = 0; j < NCAND; ++j) cand24[t*NCAND + j] = (unsigned short)(m24[j] & 0x7FFu);
    }
    __syncthreads();

    // np-exact rescore (R6-verified chain): 4 groups x 6 candidates per row
    {
        int r = t & 63, grp = t >> 6;
        float sqr = sq[r0g + r];
        float4 xrA[8];
#pragma unroll
        for (int i = 0; i < 8; ++i) xrA[i] = x4[(size_t)(r0g + r)*16 + i];
        float* kdf = (float*)cand;
#pragma unroll
        for (int m6 = 0; m6 < 6; ++m6) {
            int m = grp*6 + m6;
            int c = (int)cand24[r*NCAND + m];
            const float4* xb4 = &x4[(size_t)(rbase + c)*16];
            float dot = 0.f;
#pragma unroll
            for (int i = 0; i < 8; ++i) {
                float4 a = xrA[i]; float4 b = xb4[i];
                dot = fmaf(a.x, b.x, dot); dot = fmaf(a.y, b.y, dot);
                dot = fmaf(a.z, b.z, dot); dot = fmaf(a.w, b.w, dot);
            }
#pragma unroll
            for (int i = 8; i < 16; ++i) {
                float4 a = x4[(size_t)(r0g + r)*16 + i]; float4 b = xb4[i];
                dot = fmaf(a.x, b.x, dot); dot = fmaf(a.y, b.y, dot);
                dot = fmaf(a.z, b.z, dot); dot = fmaf(a.w, b.w, dot);
            }
            float kd = __fsub_rn(__fadd_rn(sqr, sq[rbase + c]), __fmul_rn(2.0f, dot));
            kdf[r*68 + m] = kd;
            cand[r*68 + 32 + m] = (unsigned int)c;
        }
    }
    __syncthreads();

    // exact top-16 with (key, idx) ordering
    if (t < 64) {
        float* kdf = (float*)cand;
        float dk[KNN]; int di[KNN];
#pragma unroll
        for (int j = 0; j < KNN; ++j) { dk[j] = FLT_MAX; di[j] = 0x7fffffff; }
        for (int m = 0; m < NCAND; ++m) {
            float kd = kdf[t*68 + m];
            int c = (int)cand[t*68 + 32 + m];
            bool better = (kd < dk[KNN-1]) || (kd == dk[KNN-1] && c < di[KNN-1]);
            if (better) {
#pragma unroll
                for (int j = KNN-1; j >= 1; --j) {
                    bool sh = (dk[j-1] > kd) || (dk[j-1] == kd && di[j-1] > c);
                    bool pl = (!sh) && ((dk[j] > kd) || (dk[j] == kd && di[j] > c));
                    float nk = sh ? dk[j-1] : (pl ? kd : dk[j]);
                    int ni = sh ? di[j-1] : (pl ? c : di[j]);
                    dk[j] = nk; di[j] = ni;
                }
                if ((dk[0] > kd) || (dk[0] == kd && di[0] > c)) { dk[0] = kd; di[0] = c; }
            }
        }
#pragma unroll
        for (int k = 0; k < KNN; ++k) nbr[(size_t)(r0g + t)*16 + k] = di[k];
    }
}

// Kernel 3: out[n,o] = relu(out[n,o] + max_k Bv[nbr_k, o])   (out holds A from k1)
__global__ __launch_bounds__(256) void k_combine(const float* __restrict__ Bvv,
    const int* __restrict__ nbr, float* __restrict__ out)
{
    int t = threadIdx.x;
    int row = blockIdx.x*4 + (t >> 6);
    int o = t & 63;
    int rb = (row >> 11) << 11;
    float m = -FLT_MAX;
#pragma unroll
    for (int k = 0; k < 16; ++k) {
        int c = nbr[(size_t)row*16 + k];
        m = fmaxf(m, Bvv[(size_t)(rb + c)*64 + o]);
    }
    out[(size_t)row*64 + o] = fmaxf(out[(size_t)row*64 + o] + m, 0.f);
}

extern "C" void kernel_launch(void* const* d_in, const int* in_sizes, int n_in,
                              void* d_out, int out_size, void* d_ws, size_t ws_size,
                              hipStream_t stream) {
    const float* x    = (const float*)d_in[0];
    // d_in[1] = batch (contiguous per batch; unused)
    const float* w    = (const float*)d_in[2];
    const float* bias = (const float*)d_in[3];
    float* out = (float*)d_out;

    float* Bvv  = (float*)d_ws;                       // 32 MB
    float* sqnp = Bvv + (size_t)NTOT * 64;            // 0.5 MB
    int*   nbr  = (int*)(sqnp + NTOT);                // 8 MB
    unsigned int* xbu = (unsigned int*)(nbr + (size_t)NTOT * 16);   // 16 MB bf16 x

    k_transform<<<1024, 256, 0, stream>>>(x, w, bias, out, Bvv, sqnp, xbu);
    k_topk<<<2048, 256, 0, stream>>>((const float4*)x, (const uint4*)xbu, sqnp, nbr);
    k_combine<<<NTOT/4, 256, 0, stream>>>(Bvv, nbr, out);
}

// Round 12
// 671.918 us; speedup vs baseline: 1.1409x; 1.1409x over previous
//
#include <hip/hip_runtime.h>
#include <cfloat>

#define BB 64
#define NPERB 2048
#define KNN 16
#define NTOT (BB*NPERB)
#define NCAND 24

typedef __bf16 bf16x8 __attribute__((ext_vector_type(8)));
typedef float  f32x4  __attribute__((ext_vector_type(4)));

__device__ __forceinline__ unsigned int med3u(unsigned int a, unsigned int b, unsigned int c) {
    unsigned int d;
    asm("v_med3_u32 %0, %1, %2, %3" : "=v"(d) : "v"(a), "v"(b), "v"(c));
    return d;
}

// numpy pairwise_sum (scalar 8-accumulator path) of x_f^2 over 64 contiguous fp32
__device__ __forceinline__ float np_sq64(const float* __restrict__ xs) {
    float r[8];
#pragma unroll
    for (int j = 0; j < 8; ++j) r[j] = __fmul_rn(xs[j], xs[j]);
#pragma unroll
    for (int i = 1; i < 8; ++i)
#pragma unroll
        for (int j = 0; j < 8; ++j)
            r[j] = __fadd_rn(r[j], __fmul_rn(xs[8*i + j], xs[8*i + j]));
    float t01 = __fadd_rn(r[0], r[1]);
    float t23 = __fadd_rn(r[2], r[3]);
    float t45 = __fadd_rn(r[4], r[5]);
    float t67 = __fadd_rn(r[6], r[7]);
    return __fadd_rn(__fadd_rn(t01, t23), __fadd_rn(t45, t67));
}

__device__ __forceinline__ unsigned short bf16rn(float f) {
    unsigned int u = __float_as_uint(f);
    u += 0x7fffu + ((u >> 16) & 1u);
    return (unsigned short)(u >> 16);
}
__device__ __forceinline__ unsigned int pk2(float a, float b) {
    return ((unsigned int)bf16rn(b) << 16) | (unsigned int)bf16rn(a);
}

// Kernel 1: A -> out (in place for k3), Bv, numpy-order sq, bf16 copy of x.
__global__ __launch_bounds__(256) void k_transform(const float* __restrict__ x,
    const float* __restrict__ w, const float* __restrict__ bias,
    float* __restrict__ Aout, float* __restrict__ Bvv, float* __restrict__ sqnp,
    unsigned int* __restrict__ xbu)
{
    __shared__ __align__(16) float w1mT[64*68];   // [o][f], stride 68
    __shared__ __align__(16) float w2tT[64*68];
    __shared__ __align__(16) float xs[128*64];
    int t = threadIdx.x;
    int r0 = blockIdx.x * 128;
#pragma unroll
    for (int i = 0; i < 16; ++i) {
        int e = t + i*256; int o = e >> 6; int f = e & 63;
        float w1 = w[o*128 + f];
        float w2 = w[o*128 + 64 + f];
        w1mT[o*68 + f] = w1 - w2;
        w2tT[o*68 + f] = w2;
    }
#pragma unroll
    for (int i = 0; i < 32; ++i) { int idx = t + i*256; xs[idx] = x[(size_t)r0*64 + idx]; }
    __syncthreads();
#pragma unroll
    for (int i = 0; i < 16; ++i) {
        int e = t + i*256;
        xbu[(size_t)r0*32 + e] = pk2(xs[2*e], xs[2*e + 1]);
    }
    int o = t & 63;
    int rl0 = t >> 6;
    float br = bias[o];
    for (int g = 0; g < 32; ++g) {
        int rl = g*4 + rl0;
        float a1 = 0.f, a2 = 0.f;
#pragma unroll
        for (int f4 = 0; f4 < 16; ++f4) {
            float4 xv = *(const float4*)&xs[rl*64 + f4*4];
            float4 wa = *(const float4*)&w1mT[o*68 + f4*4];
            float4 wb = *(const float4*)&w2tT[o*68 + f4*4];
            a1 = fmaf(xv.x, wa.x, a1); a1 = fmaf(xv.y, wa.y, a1);
            a1 = fmaf(xv.z, wa.z, a1); a1 = fmaf(xv.w, wa.w, a1);
            a2 = fmaf(xv.x, wb.x, a2); a2 = fmaf(xv.y, wb.y, a2);
            a2 = fmaf(xv.z, wb.z, a2); a2 = fmaf(xv.w, wb.w, a2);
        }
        int row = r0 + rl;
        Aout[(size_t)row*64 + o] = a1 + br;
        Bvv[(size_t)row*64 + o] = a2;
        if (o == 0) sqnp[row] = np_sq64(&xs[rl*64]);
    }
}

// Kernel 2: 128 rows/block, dbuf LDS B-staging, 2 row-groups per wave (2x MFMA+filter per
// staged byte), med3 flat-16 filter -> 2-pass merge top-24 -> np-exact rescore -> top-16.
__global__ __launch_bounds__(256, 5) void k_topk(const float4* __restrict__ x4,
    const uint4* __restrict__ xbu, const float* __restrict__ sq, int* __restrict__ nbr)
{
    // phase1: bsh0 0..9216 | bsh1 9216..18432 | sqc 18432..18944 (2x64 floats)
    // phase2: cand 0..17408 (64 rows x 68) | cand24 17408..23552 (128 x 24 ushort)
    __shared__ __align__(16) char smem[23552];
    unsigned short* bsh0 = (unsigned short*)smem;
    unsigned short* bsh1 = (unsigned short*)(smem + 9216);
    float* sqc           = (float*)(smem + 18432);
    unsigned int* cand   = (unsigned int*)smem;
    unsigned short* cand24 = (unsigned short*)(smem + 17408);

    int t = threadIdx.x;
    int lane = t & 63;
    int w = t >> 6;
    int ln = lane & 15, qd = lane >> 4;
    int batch = blockIdx.x >> 4;
    int strip = blockIdx.x & 15;
    int rbase = batch * NPERB;
    int r0g = rbase + strip * 128;

    // two row-groups per wave: rows w*32+ln and w*32+16+ln, fragments direct from global
    int rowA = r0g + w*32 + ln;
    int rowB = rowA + 16;
    bf16x8 rfA0, rfA1, rfB0, rfB1;
    { uint4 v = xbu[(size_t)rowA*8 + qd];     rfA0 = *(bf16x8*)&v; }
    { uint4 v = xbu[(size_t)rowA*8 + 4 + qd]; rfA1 = *(bf16x8*)&v; }
    { uint4 v = xbu[(size_t)rowB*8 + qd];     rfB0 = *(bf16x8*)&v; }
    { uint4 v = xbu[(size_t)rowB*8 + 4 + qd]; rfB1 = *(bf16x8*)&v; }
    float sqr16A = sq[rowA] + 16.f;
    float sqr16B = sq[rowB] + 16.f;

    // prefetch tile0 -> regs
    uint4 pf0, pf1; float sqpf;
    {
        const uint4* src = xbu + (size_t)rbase * 8;
        pf0 = src[t]; pf1 = src[t + 256];
        sqpf = (t < 64) ? sq[rbase + t] : 0.f;
    }
    // write tile0 -> bsh0, prefetch tile1
    *(uint4*)&bsh0[(t >> 3)*72 + (t & 7)*8] = pf0;
    { int l1 = t + 256; *(uint4*)&bsh0[(l1 >> 3)*72 + (l1 & 7)*8] = pf1; }
    if (t < 64) sqc[t] = sqpf;
    {
        const uint4* src = xbu + ((size_t)rbase + 64) * 8;
        pf0 = src[t]; pf1 = src[t + 256];
        sqpf = (t < 64) ? sq[rbase + 64 + t] : 0.f;
    }
    __syncthreads();

    unsigned int ksA[16], ksB[16];
#pragma unroll
    for (int j = 0; j < 16; ++j) { ksA[j] = 0xFFFFFFFFu; ksB[j] = 0xFFFFFFFFu; }

    for (int ct = 0; ct < 32; ++ct) {
        unsigned short* bcur = (ct & 1) ? bsh1 : bsh0;
        const float* sqcur = sqc + (ct & 1)*64;
#pragma unroll
        for (int ct2 = 0; ct2 < 4; ++ct2) {
            int pt = ct2*16 + ln;
            bf16x8 a0 = *(const bf16x8*)&bcur[pt*72 + qd*8];
            bf16x8 a1 = *(const bf16x8*)&bcur[pt*72 + 32 + qd*8];
            f32x4 accA = {0.f, 0.f, 0.f, 0.f};
            accA = __builtin_amdgcn_mfma_f32_16x16x32_bf16(a0, rfA0, accA, 0, 0, 0);
            accA = __builtin_amdgcn_mfma_f32_16x16x32_bf16(a1, rfA1, accA, 0, 0, 0);
            f32x4 accB = {0.f, 0.f, 0.f, 0.f};
            accB = __builtin_amdgcn_mfma_f32_16x16x32_bf16(a0, rfB0, accB, 0, 0, 0);
            accB = __builtin_amdgcn_mfma_f32_16x16x32_bf16(a1, rfB1, accB, 0, 0, 0);
            f32x4 sc4 = *(const f32x4*)&sqcur[ct2*16 + qd*4];
            int idxb = ct*64 + ct2*16 + qd*4;
#pragma unroll
            for (int j = 0; j < 4; ++j) {
                float sA = fmaf(-2.f, accA[j], sc4[j] + sqr16A);
                unsigned int uA = (__float_as_uint(sA) & 0xFFFFF800u) | (unsigned int)(idxb + j);
#pragma unroll
                for (int jj = 15; jj >= 1; --jj) ksA[jj] = med3u(uA, ksA[jj-1], ksA[jj]);
                ksA[0] = min(ksA[0], uA);
                float sB = fmaf(-2.f, accB[j], sc4[j] + sqr16B);
                unsigned int uB = (__float_as_uint(sB) & 0xFFFFF800u) | (unsigned int)(idxb + j);
#pragma unroll
                for (int jj = 15; jj >= 1; --jj) ksB[jj] = med3u(uB, ksB[jj-1], ksB[jj]);
                ksB[0] = min(ksB[0], uB);
            }
        }
        if (ct < 31) {
            unsigned short* bnext = (ct & 1) ? bsh0 : bsh1;
            *(uint4*)&bnext[(t >> 3)*72 + (t & 7)*8] = pf0;
            { int l1 = t + 256; *(uint4*)&bnext[(l1 >> 3)*72 + (l1 & 7)*8] = pf1; }
            if (t < 64) sqc[((ct + 1) & 1)*64 + t] = sqpf;
            if (ct < 30) {
                const uint4* src = xbu + ((size_t)rbase + (ct + 2)*64) * 8;
                pf0 = src[t]; pf1 = src[t + 256];
                sqpf = (t < 64) ? sq[rbase + (ct + 2)*64 + t] : 0.f;
            }
        }
        __syncthreads();
    }

    // two-pass merge: half h covers local rows h*64..h*64+63 (waves 2h, 2h+1)
#pragma unroll
    for (int h = 0; h < 2; ++h) {
        if ((w >> 1) == h) {
            int rlocA = (w & 1)*32 + ln;        // local row within half
#pragma unroll
            for (int j = 0; j < 16; ++j) cand[rlocA*68 + qd*16 + j] = ksA[j];
#pragma unroll
            for (int j = 0; j < 16; ++j) cand[(rlocA + 16)*68 + qd*16 + j] = ksB[j];
        }
        __syncthreads();
        if (t < 64) {
            unsigned int m24[NCAND];
#pragma unroll
            for (int j = 0; j < NCAND; ++j) m24[j] = 0xFFFFFFFFu;
            for (int i = 0; i < 64; ++i) {
                unsigned int u = cand[t*68 + i];
#pragma unroll
                for (int jj = NCAND-1; jj >= 1; --jj) m24[jj] = med3u(u, m24[jj-1], m24[jj]);
                m24[0] = min(m24[0], u);
            }
#pragma unroll
            for (int j = 0; j < NCAND; ++j)
                cand24[(h*64 + t)*NCAND + j] = (unsigned short)(m24[j] & 0x7FFu);
        }
        __syncthreads();
    }

    // np-exact rescore (R6-verified chain): 2 halves x 12 candidates per row; kd -> LDS
    {
        int r = t & 127, half = t >> 7;
        int gr = r0g + r;
        float sqr = sq[gr];
        float4 xrA[8];
#pragma unroll
        for (int i = 0; i < 8; ++i) xrA[i] = x4[(size_t)gr*16 + i];
        float* kdf = (float*)cand;               // 128 x 24 floats = 12288 B
#pragma unroll
        for (int m12 = 0; m12 < 12; ++m12) {
            int m = half*12 + m12;
            int c = (int)cand24[r*NCAND + m];
            const float4* xb4 = &x4[(size_t)(rbase + c)*16];
            float dot = 0.f;
#pragma unroll
            for (int i = 0; i < 8; ++i) {
                float4 a = xrA[i]; float4 b = xb4[i];
                dot = fmaf(a.x, b.x, dot); dot = fmaf(a.y, b.y, dot);
                dot = fmaf(a.z, b.z, dot); dot = fmaf(a.w, b.w, dot);
            }
#pragma unroll
            for (int i = 8; i < 16; ++i) {
                float4 a = x4[(size_t)gr*16 + i]; float4 b = xb4[i];
                dot = fmaf(a.x, b.x, dot); dot = fmaf(a.y, b.y, dot);
                dot = fmaf(a.z, b.z, dot); dot = fmaf(a.w, b.w, dot);
            }
            float kd = __fsub_rn(__fadd_rn(sqr, sq[rbase + c]), __fmul_rn(2.0f, dot));
            kdf[r*24 + m] = kd;
        }
    }
    __syncthreads();

    // exact top-16 with (key, idx) ordering
    if (t < 128) {
        float* kdf = (float*)cand;
        float dk[KNN]; int di[KNN];
#pragma unroll
        for (int j = 0; j < KNN; ++j) { dk[j] = FLT_MAX; di[j] = 0x7fffffff; }
        for (int m = 0; m < NCAND; ++m) {
            float kd = kdf[t*24 + m];
            int c = (int)cand24[t*NCAND + m];
            bool better = (kd < dk[KNN-1]) || (kd == dk[KNN-1] && c < di[KNN-1]);
            if (better) {
#pragma unroll
                for (int j = KNN-1; j >= 1; --j) {
                    bool sh = (dk[j-1] > kd) || (dk[j-1] == kd && di[j-1] > c);
                    bool pl = (!sh) && ((dk[j] > kd) || (dk[j] == kd && di[j] > c));
                    float nk = sh ? dk[j-1] : (pl ? kd : dk[j]);
                    int ni = sh ? di[j-1] : (pl ? c : di[j]);
                    dk[j] = nk; di[j] = ni;
                }
                if ((dk[0] > kd) || (dk[0] == kd && di[0] > c)) { dk[0] = kd; di[0] = c; }
            }
        }
#pragma unroll
        for (int k = 0; k < KNN; ++k) nbr[(size_t)(r0g + t)*16 + k] = di[k];
    }
}

// Kernel 3: out[n,o] = relu(out[n,o] + max_k Bv[nbr_k, o])   (out holds A from k1)
__global__ __launch_bounds__(256) void k_combine(const float* __restrict__ Bvv,
    const int* __restrict__ nbr, float* __restrict__ out)
{
    int t = threadIdx.x;
    int row = blockIdx.x*4 + (t >> 6);
    int o = t & 63;
    int rb = (row >> 11) << 11;
    float m = -FLT_MAX;
#pragma unroll
    for (int k = 0; k < 16; ++k) {
        int c = nbr[(size_t)row*16 + k];
        m = fmaxf(m, Bvv[(size_t)(rb + c)*64 + o]);
    }
    out[(size_t)row*64 + o] = fmaxf(out[(size_t)row*64 + o] + m, 0.f);
}

extern "C" void kernel_launch(void* const* d_in, const int* in_sizes, int n_in,
                              void* d_out, int out_size, void* d_ws, size_t ws_size,
                              hipStream_t stream) {
    const float* x    = (const float*)d_in[0];
    // d_in[1] = batch (contiguous per batch; unused)
    const float* w    = (const float*)d_in[2];
    const float* bias = (const float*)d_in[3];
    float* out = (float*)d_out;

    float* Bvv  = (float*)d_ws;                       // 32 MB
    float* sqnp = Bvv + (size_t)NTOT * 64;            // 0.5 MB
    int*   nbr  = (int*)(sqnp + NTOT);                // 8 MB
    unsigned int* xbu = (unsigned int*)(nbr + (size_t)NTOT * 16);   // 16 MB bf16 x

    k_transform<<<1024, 256, 0, stream>>>(x, w, bias, out, Bvv, sqnp, xbu);
    k_topk<<<1024, 256, 0, stream>>>((const float4*)x, (const uint4*)xbu, sqnp, nbr);
    k_combine<<<NTOT/4, 256, 0, stream>>>(Bvv, nbr, out);
}